// Round 2
// baseline (2659.312 us; speedup 1.0000x reference)
//
#include <hip/hip_runtime.h>
#include <hip/hip_bf16.h>
#include <stdint.h>

typedef __attribute__((ext_vector_type(8))) short short8;       // 8 bf16 (MFMA frag)
typedef __attribute__((ext_vector_type(4))) float f32x4;
typedef __attribute__((ext_vector_type(4))) unsigned short u16x4;
typedef __attribute__((ext_vector_type(8))) unsigned short u16x8;

#define BM 128
#define BN 128
#define BK 64

static __device__ __forceinline__ unsigned short f2bf(float f) {
  union { float f; unsigned int u; } c; c.f = f;
  unsigned int u = c.u;
  u += 0x7FFFu + ((u >> 16) & 1u);
  return (unsigned short)(u >> 16);
}

static __device__ __forceinline__ f32x4 mfma_bf16(short8 a, short8 b, f32x4 c) {
  return __builtin_amdgcn_mfma_f32_16x16x32_bf16(a, b, c, 0, 0, 0);
}

// async global->LDS, 16B per lane. LDS dest = wave-uniform base + lane*16.
static __device__ __forceinline__ void gl_lds16(const void* g, void* lds) {
  __builtin_amdgcn_global_load_lds(
      (const __attribute__((address_space(1))) void*)(unsigned long long)(uintptr_t)g,
      (__attribute__((address_space(3))) void*)(unsigned int)(uintptr_t)lds,
      16, 0, 0);
}

// ---------------------------------------------------------------------------
// Convert fp8-style quantized fp32 weight [N][K] + block scale [N/128][K/128]
// to dequantized bf16 [N][K].
// ---------------------------------------------------------------------------
__global__ void k_cvt_w(const float* __restrict__ w, const float* __restrict__ s,
                        unsigned short* __restrict__ o, int N, int K) {
  const int KB = K >> 7;
  const size_t total = ((size_t)N * K) >> 3;
  for (size_t i = (size_t)blockIdx.x * blockDim.x + threadIdx.x; i < total;
       i += (size_t)gridDim.x * blockDim.x) {
    const size_t e = i << 3;
    const int n = (int)(e / K);
    const int k = (int)(e % K);
    const float sc = s[(n >> 7) * KB + (k >> 7)];
    f32x4 a = *(const f32x4*)(w + e);
    f32x4 b = *(const f32x4*)(w + e + 4);
    u16x8 q;
    #pragma unroll
    for (int j = 0; j < 4; ++j) { q[j] = f2bf(a[j] * sc); q[4 + j] = f2bf(b[j] * sc); }
    *(u16x8*)(o + e) = q;
  }
}

// fp32 -> bf16 straight convert (activations; act_quant dequant is identity)
__global__ void k_cvt_x(const float* __restrict__ x, unsigned short* __restrict__ o,
                        size_t total8) {
  for (size_t i = (size_t)blockIdx.x * blockDim.x + threadIdx.x; i < total8;
       i += (size_t)gridDim.x * blockDim.x) {
    const size_t e = i << 3;
    f32x4 a = *(const f32x4*)(x + e);
    f32x4 b = *(const f32x4*)(x + e + 4);
    u16x8 q;
    #pragma unroll
    for (int j = 0; j < 4; ++j) { q[j] = f2bf(a[j]); q[4 + j] = f2bf(b[j]); }
    *(u16x8*)(o + e) = q;
  }
}

// ---------------------------------------------------------------------------
// m97-structure fused gate+up GEMM + SwiGLU. All operands bf16.
//   h = silu(xb @ w1b^T) * (xb @ w3b^T)   -> bf16 [M][N]
// ---------------------------------------------------------------------------
__global__ __launch_bounds__(256, 3)
void k_gateup2(const unsigned short* __restrict__ xb,
               const unsigned short* __restrict__ w1b,
               const unsigned short* __restrict__ w3b,
               unsigned short* __restrict__ h,
               int M, int N, int K) {
  __shared__ unsigned short sA[BM * BK];    // linear [128][64] bf16, 16KB
  __shared__ unsigned short sB1[BM * BK];
  __shared__ unsigned short sB3[BM * BK];

  const int t    = threadIdx.x;
  const int lane = t & 63;
  const int w    = t >> 6;
  const int wm   = w >> 1, wn = w & 1;
  const int lr   = lane & 15;
  const int kg   = lane >> 4;
  const int bn   = blockIdx.x, bm = blockIdx.y;

  const int srow  = lane >> 3;          // 0..7 row within an 8-row chunk
  const int scolb = (lane & 7) * 16;    // byte col within 128B row

  f32x4 accg[4][4], accu[4][4];
  #pragma unroll
  for (int i = 0; i < 4; ++i)
    #pragma unroll
    for (int j = 0; j < 4; ++j)
      #pragma unroll
      for (int e = 0; e < 4; ++e) { accg[i][j][e] = 0.0f; accu[i][j][e] = 0.0f; }

  const char* gA = (const char*)(xb  + (size_t)bm * BM * K);
  const char* g1 = (const char*)(w1b + (size_t)bn * BN * K);
  const char* g3 = (const char*)(w3b + (size_t)bn * BN * K);
  const size_t ldb = (size_t)K * 2;     // row stride bytes

  for (int kt = 0; kt < K; kt += BK) {
    // stage 3 tiles: 16 chunks each, 4 waves x 4 iters, 1KB per wave-issue
    #pragma unroll
    for (int i = 0; i < 4; ++i) {
      const int c = i * 4 + w;
      const size_t go = (size_t)(c * 8 + srow) * ldb + (size_t)kt * 2 + scolb;
      gl_lds16(gA + go, sA  + c * 512);
      gl_lds16(g1 + go, sB1 + c * 512);
      gl_lds16(g3 + go, sB3 + c * 512);
    }
    __syncthreads();   // vmcnt(0) drain emitted by compiler

    #pragma unroll
    for (int ks = 0; ks < 2; ++ks) {
      const int ko = ks * 32 + kg * 8;
      short8 af[4], b1f[4], b3f[4];
      #pragma unroll
      for (int mi = 0; mi < 4; ++mi)
        af[mi] = *(const short8*)(sA + (wm * 64 + mi * 16 + lr) * BK + ko);
      #pragma unroll
      for (int ni = 0; ni < 4; ++ni) {
        b1f[ni] = *(const short8*)(sB1 + (wn * 64 + ni * 16 + lr) * BK + ko);
        b3f[ni] = *(const short8*)(sB3 + (wn * 64 + ni * 16 + lr) * BK + ko);
      }
      #pragma unroll
      for (int mi = 0; mi < 4; ++mi)
        #pragma unroll
        for (int ni = 0; ni < 4; ++ni) {
          accg[mi][ni] = mfma_bf16(af[mi], b1f[ni], accg[mi][ni]);
          accu[mi][ni] = mfma_bf16(af[mi], b3f[ni], accu[mi][ni]);
        }
    }
    __syncthreads();
  }

  // epilogue: C/D map col=lane&15, row=(lane>>4)*4+j  [m89-verified, R1-passed]
  const int r0 = bm * BM + wm * 64 + kg * 4;
  const int c0 = bn * BN + wn * 64 + lr;
  #pragma unroll
  for (int mi = 0; mi < 4; ++mi)
    #pragma unroll
    for (int ni = 0; ni < 4; ++ni)
      #pragma unroll
      for (int j = 0; j < 4; ++j) {
        const float g  = accg[mi][ni][j];
        const float u  = accu[mi][ni][j];
        const float sg = g / (1.0f + __expf(-g));
        h[(size_t)(r0 + mi * 16 + j) * N + (c0 + ni * 16)] = f2bf(sg * u);
      }
}

// ---------------------------------------------------------------------------
// m97-structure down GEMM: y = h @ w2b^T, fp32 out.
// ---------------------------------------------------------------------------
__global__ __launch_bounds__(256, 3)
void k_down2(const unsigned short* __restrict__ h,
             const unsigned short* __restrict__ w2b,
             float* __restrict__ y,
             int M, int N, int K) {
  __shared__ unsigned short sA[BM * BK];
  __shared__ unsigned short sB[BM * BK];

  const int t    = threadIdx.x;
  const int lane = t & 63;
  const int w    = t >> 6;
  const int wm   = w >> 1, wn = w & 1;
  const int lr   = lane & 15;
  const int kg   = lane >> 4;
  const int bn   = blockIdx.x, bm = blockIdx.y;

  const int srow  = lane >> 3;
  const int scolb = (lane & 7) * 16;

  f32x4 acc[4][4];
  #pragma unroll
  for (int i = 0; i < 4; ++i)
    #pragma unroll
    for (int j = 0; j < 4; ++j)
      #pragma unroll
      for (int e = 0; e < 4; ++e) acc[i][j][e] = 0.0f;

  const char* gA = (const char*)(h   + (size_t)bm * BM * K);
  const char* gB = (const char*)(w2b + (size_t)bn * BN * K);
  const size_t ldb = (size_t)K * 2;

  for (int kt = 0; kt < K; kt += BK) {
    #pragma unroll
    for (int i = 0; i < 4; ++i) {
      const int c = i * 4 + w;
      const size_t go = (size_t)(c * 8 + srow) * ldb + (size_t)kt * 2 + scolb;
      gl_lds16(gA + go, sA + c * 512);
      gl_lds16(gB + go, sB + c * 512);
    }
    __syncthreads();

    #pragma unroll
    for (int ks = 0; ks < 2; ++ks) {
      const int ko = ks * 32 + kg * 8;
      short8 af[4], bf[4];
      #pragma unroll
      for (int mi = 0; mi < 4; ++mi)
        af[mi] = *(const short8*)(sA + (wm * 64 + mi * 16 + lr) * BK + ko);
      #pragma unroll
      for (int ni = 0; ni < 4; ++ni)
        bf[ni] = *(const short8*)(sB + (wn * 64 + ni * 16 + lr) * BK + ko);
      #pragma unroll
      for (int mi = 0; mi < 4; ++mi)
        #pragma unroll
        for (int ni = 0; ni < 4; ++ni)
          acc[mi][ni] = mfma_bf16(af[mi], bf[ni], acc[mi][ni]);
    }
    __syncthreads();
  }

  const int r0 = bm * BM + wm * 64 + kg * 4;
  const int c0 = bn * BN + wn * 64 + lr;
  #pragma unroll
  for (int mi = 0; mi < 4; ++mi)
    #pragma unroll
    for (int ni = 0; ni < 4; ++ni)
      #pragma unroll
      for (int j = 0; j < 4; ++j)
        y[(size_t)(r0 + mi * 16 + j) * N + (c0 + ni * 16)] = acc[mi][ni][j];
}

// ===========================================================================
// Fallback path (R1 kernels) if ws_size can't hold bf16 weight copies.
// ===========================================================================
#define LDK 72
__global__ __launch_bounds__(256, 2)
void k_gateup_fb(const float* __restrict__ x,
                 const float* __restrict__ w1, const float* __restrict__ w1s,
                 const float* __restrict__ w3, const float* __restrict__ w3s,
                 unsigned short* __restrict__ h,
                 int M, int N, int K) {
  __shared__ unsigned short sA[BM][LDK];
  __shared__ unsigned short sB1[BM][LDK];
  __shared__ unsigned short sB3[BM][LDK];
  const int t = threadIdx.x, bn = blockIdx.x, bm = blockIdx.y;
  const int lane = t & 63, wm = (t >> 6) >> 1, wn = (t >> 6) & 1;
  const int lr = lane & 15, kg = lane >> 4;
  f32x4 accg[4][4], accu[4][4];
  #pragma unroll
  for (int i = 0; i < 4; ++i)
    #pragma unroll
    for (int j = 0; j < 4; ++j)
      #pragma unroll
      for (int e = 0; e < 4; ++e) { accg[i][j][e] = 0.0f; accu[i][j][e] = 0.0f; }
  const int sc = (t & 15) << 2, sr0 = t >> 4, KB = K >> 7;
  const float* pA = x  + (size_t)(bm * BM + sr0) * K + sc;
  const float* p1 = w1 + (size_t)(bn * BN + sr0) * K + sc;
  const float* p3 = w3 + (size_t)(bn * BN + sr0) * K + sc;
  for (int kt = 0; kt < K; kt += BK) {
    const float s1 = w1s[bn * KB + (kt >> 7)];
    const float s3 = w3s[bn * KB + (kt >> 7)];
    #pragma unroll
    for (int i = 0; i < 8; ++i) {
      const int r = sr0 + i * 16;
      const size_t go = (size_t)i * 16 * K + kt;
      f32x4 va = *(const f32x4*)(pA + go);
      f32x4 v1 = *(const f32x4*)(p1 + go);
      f32x4 v3 = *(const f32x4*)(p3 + go);
      u16x4 qa, q1, q3;
      #pragma unroll
      for (int e = 0; e < 4; ++e) { qa[e] = f2bf(va[e]); q1[e] = f2bf(v1[e] * s1); q3[e] = f2bf(v3[e] * s3); }
      *(u16x4*)(&sA[r][sc]) = qa; *(u16x4*)(&sB1[r][sc]) = q1; *(u16x4*)(&sB3[r][sc]) = q3;
    }
    __syncthreads();
    #pragma unroll
    for (int ks = 0; ks < 2; ++ks) {
      const int ko = ks * 32 + kg * 8;
      short8 af[4], b1f[4], b3f[4];
      #pragma unroll
      for (int mi = 0; mi < 4; ++mi) af[mi] = *(const short8*)(&sA[wm * 64 + mi * 16 + lr][ko]);
      #pragma unroll
      for (int ni = 0; ni < 4; ++ni) { b1f[ni] = *(const short8*)(&sB1[wn * 64 + ni * 16 + lr][ko]); b3f[ni] = *(const short8*)(&sB3[wn * 64 + ni * 16 + lr][ko]); }
      #pragma unroll
      for (int mi = 0; mi < 4; ++mi)
        #pragma unroll
        for (int ni = 0; ni < 4; ++ni) { accg[mi][ni] = mfma_bf16(af[mi], b1f[ni], accg[mi][ni]); accu[mi][ni] = mfma_bf16(af[mi], b3f[ni], accu[mi][ni]); }
    }
    __syncthreads();
  }
  const int r0 = bm * BM + wm * 64 + kg * 4;
  const int c0 = bn * BN + wn * 64 + lr;
  #pragma unroll
  for (int mi = 0; mi < 4; ++mi)
    #pragma unroll
    for (int ni = 0; ni < 4; ++ni)
      #pragma unroll
      for (int j = 0; j < 4; ++j) {
        const float g = accg[mi][ni][j], u = accu[mi][ni][j];
        h[(size_t)(r0 + mi * 16 + j) * N + (c0 + ni * 16)] = f2bf((g / (1.0f + __expf(-g))) * u);
      }
}

__global__ __launch_bounds__(256, 2)
void k_down_fb(const unsigned short* __restrict__ h,
               const float* __restrict__ w2, const float* __restrict__ w2s,
               float* __restrict__ y, int M, int N, int K) {
  __shared__ unsigned short sA[BM][LDK];
  __shared__ unsigned short sB[BM][LDK];
  const int t = threadIdx.x, bn = blockIdx.x, bm = blockIdx.y;
  const int lane = t & 63, wm = (t >> 6) >> 1, wn = (t >> 6) & 1;
  const int lr = lane & 15, kg = lane >> 4;
  f32x4 acc[4][4];
  #pragma unroll
  for (int i = 0; i < 4; ++i)
    #pragma unroll
    for (int j = 0; j < 4; ++j)
      #pragma unroll
      for (int e = 0; e < 4; ++e) acc[i][j][e] = 0.0f;
  const int ac = (t & 7) << 3, ar0 = t >> 3;
  const int sc = (t & 15) << 2, sr0 = t >> 4, KB = K >> 7;
  const unsigned short* pA = h + (size_t)(bm * BM + ar0) * K + ac;
  const float* pB = w2 + (size_t)(bn * BN + sr0) * K + sc;
  for (int kt = 0; kt < K; kt += BK) {
    const float s2 = w2s[bn * KB + (kt >> 7)];
    #pragma unroll
    for (int i = 0; i < 4; ++i) { u16x8 v = *(const u16x8*)(pA + (size_t)i * 32 * K + kt); *(u16x8*)(&sA[ar0 + i * 32][ac]) = v; }
    #pragma unroll
    for (int i = 0; i < 8; ++i) {
      f32x4 v = *(const f32x4*)(pB + (size_t)i * 16 * K + kt);
      u16x4 q;
      #pragma unroll
      for (int e = 0; e < 4; ++e) q[e] = f2bf(v[e] * s2);
      *(u16x4*)(&sB[sr0 + i * 16][sc]) = q;
    }
    __syncthreads();
    #pragma unroll
    for (int ks = 0; ks < 2; ++ks) {
      const int ko = ks * 32 + kg * 8;
      short8 af[4], bf[4];
      #pragma unroll
      for (int mi = 0; mi < 4; ++mi) af[mi] = *(const short8*)(&sA[wm * 64 + mi * 16 + lr][ko]);
      #pragma unroll
      for (int ni = 0; ni < 4; ++ni) bf[ni] = *(const short8*)(&sB[wn * 64 + ni * 16 + lr][ko]);
      #pragma unroll
      for (int mi = 0; mi < 4; ++mi)
        #pragma unroll
        for (int ni = 0; ni < 4; ++ni) acc[mi][ni] = mfma_bf16(af[mi], bf[ni], acc[mi][ni]);
    }
    __syncthreads();
  }
  const int r0 = bm * BM + wm * 64 + kg * 4;
  const int c0 = bn * BN + wn * 64 + lr;
  #pragma unroll
  for (int mi = 0; mi < 4; ++mi)
    #pragma unroll
    for (int ni = 0; ni < 4; ++ni)
      #pragma unroll
      for (int j = 0; j < 4; ++j)
        y[(size_t)(r0 + mi * 16 + j) * N + (c0 + ni * 16)] = acc[mi][ni][j];
}

extern "C" void kernel_launch(void* const* d_in, const int* in_sizes, int n_in,
                              void* d_out, int out_size, void* d_ws, size_t ws_size,
                              hipStream_t stream) {
  const float* x   = (const float*)d_in[0];
  const float* w1  = (const float*)d_in[1];
  const float* w1s = (const float*)d_in[2];
  const float* w3  = (const float*)d_in[3];
  const float* w3s = (const float*)d_in[4];
  const float* w2  = (const float*)d_in[5];
  const float* w2s = (const float*)d_in[6];
  float* y = (float*)d_out;

  const int D = 4096, I = 14336;
  const int T = in_sizes[0] / D;          // 2048

  const size_t xbB  = (size_t)T * D * 2;          //  16.8 MB
  const size_t wB   = (size_t)I * D * 2;          // 117.4 MB (each of w1,w3,w2)
  const size_t hB   = (size_t)T * I * 2;          //  58.7 MB
  const size_t need = xbB + 3 * wB + hB;          // ~408 MB

  if (ws_size >= need) {
    char* ws = (char*)d_ws;
    unsigned short* xb  = (unsigned short*)(ws);
    unsigned short* w1b = (unsigned short*)(ws + xbB);
    unsigned short* w3b = (unsigned short*)(ws + xbB + wB);
    unsigned short* w2b = (unsigned short*)(ws + xbB + 2 * wB);
    unsigned short* h   = (unsigned short*)(ws + xbB + 3 * wB);

    k_cvt_x<<<2048, 256, 0, stream>>>(x, xb, ((size_t)T * D) >> 3);
    k_cvt_w<<<2048, 256, 0, stream>>>(w1, w1s, w1b, I, D);
    k_cvt_w<<<2048, 256, 0, stream>>>(w3, w3s, w3b, I, D);
    k_cvt_w<<<2048, 256, 0, stream>>>(w2, w2s, w2b, D, I);

    k_gateup2<<<dim3(I / BN, T / BM), dim3(256), 0, stream>>>(xb, w1b, w3b, h, T, I, D);
    k_down2  <<<dim3(D / BN, T / BM), dim3(256), 0, stream>>>(h, w2b, y, T, D, I);
  } else {
    unsigned short* h = (unsigned short*)d_ws;    // 58.7 MB
    k_gateup_fb<<<dim3(I / BN, T / BM), dim3(256), 0, stream>>>(x, w1, w1s, w3, w3s, h, T, I, D);
    k_down_fb  <<<dim3(D / BN, T / BM), dim3(256), 0, stream>>>(h, w2, w2s, y, T, D, I);
  }
}

// Round 3
// 2479.030 us; speedup vs baseline: 1.0727x; 1.0727x over previous
//
#include <hip/hip_runtime.h>
#include <hip/hip_bf16.h>
#include <stdint.h>

typedef __attribute__((ext_vector_type(8))) short short8;       // 8 bf16 (MFMA frag)
typedef __attribute__((ext_vector_type(4))) float f32x4;
typedef __attribute__((ext_vector_type(4))) unsigned short u16x4;
typedef __attribute__((ext_vector_type(8))) unsigned short u16x8;

#define BM 128
#define BN 128
#define BK 64
#define HLD 136   // h-tile epilogue LDS stride (128 + 8 pad), 272B row = 17x16B

static __device__ __forceinline__ unsigned short f2bf(float f) {
  union { float f; unsigned int u; } c; c.f = f;
  unsigned int u = c.u;
  u += 0x7FFFu + ((u >> 16) & 1u);
  return (unsigned short)(u >> 16);
}

static __device__ __forceinline__ f32x4 mfma_bf16(short8 a, short8 b, f32x4 c) {
  return __builtin_amdgcn_mfma_f32_16x16x32_bf16(a, b, c, 0, 0, 0);
}

// async global->LDS, 16B per lane. LDS dest = wave-uniform base + lane*16.
static __device__ __forceinline__ void gl_lds16(const void* g, void* lds) {
  __builtin_amdgcn_global_load_lds(
      (const __attribute__((address_space(1))) void*)(unsigned long long)(uintptr_t)g,
      (__attribute__((address_space(3))) void*)(unsigned int)(uintptr_t)lds,
      16, 0, 0);
}

// ---------------------------------------------------------------------------
// fp32 quantized weight [N][K] + block scale [N/128][K/128] -> dequant bf16
// ---------------------------------------------------------------------------
__global__ void k_cvt_w(const float* __restrict__ w, const float* __restrict__ s,
                        unsigned short* __restrict__ o, int N, int K) {
  const int KB = K >> 7;
  const size_t total = ((size_t)N * K) >> 3;
  for (size_t i = (size_t)blockIdx.x * blockDim.x + threadIdx.x; i < total;
       i += (size_t)gridDim.x * blockDim.x) {
    const size_t e = i << 3;
    const int n = (int)(e / K);
    const int k = (int)(e % K);
    const float sc = s[(n >> 7) * KB + (k >> 7)];
    f32x4 a = *(const f32x4*)(w + e);
    f32x4 b = *(const f32x4*)(w + e + 4);
    u16x8 q;
    #pragma unroll
    for (int j = 0; j < 4; ++j) { q[j] = f2bf(a[j] * sc); q[4 + j] = f2bf(b[j] * sc); }
    *(u16x8*)(o + e) = q;
  }
}

__global__ void k_cvt_x(const float* __restrict__ x, unsigned short* __restrict__ o,
                        size_t total8) {
  for (size_t i = (size_t)blockIdx.x * blockDim.x + threadIdx.x; i < total8;
       i += (size_t)gridDim.x * blockDim.x) {
    const size_t e = i << 3;
    f32x4 a = *(const f32x4*)(x + e);
    f32x4 b = *(const f32x4*)(x + e + 4);
    u16x8 q;
    #pragma unroll
    for (int j = 0; j < 4; ++j) { q[j] = f2bf(a[j]); q[4 + j] = f2bf(b[j]); }
    *(u16x8*)(o + e) = q;
  }
}

// ---------------------------------------------------------------------------
// Fused gate+up GEMM + SwiGLU, m97 structure, bf16 operands.
//   h = silu(xb @ w1b^T) * (xb @ w3b^T)   -> bf16 [M][N]
// 1D grid, XCD-chunked + bm-fastest ordering for weight L2 reuse.
// ---------------------------------------------------------------------------
__global__ __launch_bounds__(256, 3)
void k_gateup2(const unsigned short* __restrict__ xb,
               const unsigned short* __restrict__ w1b,
               const unsigned short* __restrict__ w3b,
               unsigned short* __restrict__ h,
               int M, int N, int K) {
  __shared__ unsigned short smem[3 * BM * BK];   // 48KB
  unsigned short* sA  = smem;
  unsigned short* sB1 = smem + BM * BK;
  unsigned short* sB3 = smem + 2 * BM * BK;

  const int t    = threadIdx.x;
  const int lane = t & 63;
  const int w    = t >> 6;
  const int wm   = w >> 1, wn = w & 1;
  const int lr   = lane & 15;
  const int kg   = lane >> 4;

  // XCD-chunked bijective swizzle (nwg % 8 == 0), bm fastest within chunk
  const int nwg = gridDim.x;
  const int per = nwg >> 3;
  const int wg  = (int)blockIdx.x;
  const int swz = (wg & 7) * per + (wg >> 3);
  const int bm  = swz & 15;        // M/BM = 16
  const int bn  = swz >> 4;

  const int srow  = lane >> 3;          // row within 8-row chunk
  const int scolb = (lane & 7) * 16;    // byte col within 128B row

  f32x4 accg[4][4], accu[4][4];
  #pragma unroll
  for (int i = 0; i < 4; ++i)
    #pragma unroll
    for (int j = 0; j < 4; ++j)
      #pragma unroll
      for (int e = 0; e < 4; ++e) { accg[i][j][e] = 0.0f; accu[i][j][e] = 0.0f; }

  const char* gA = (const char*)(xb  + (size_t)bm * BM * K);
  const char* g1 = (const char*)(w1b + (size_t)bn * BN * K);
  const char* g3 = (const char*)(w3b + (size_t)bn * BN * K);
  const size_t ldb = (size_t)K * 2;

  for (int kt = 0; kt < K; kt += BK) {
    #pragma unroll
    for (int i = 0; i < 4; ++i) {
      const int c = i * 4 + w;
      const size_t go = (size_t)(c * 8 + srow) * ldb + (size_t)kt * 2 + scolb;
      gl_lds16(gA + go, sA  + c * 512);
      gl_lds16(g1 + go, sB1 + c * 512);
      gl_lds16(g3 + go, sB3 + c * 512);
    }
    __syncthreads();

    #pragma unroll
    for (int ks = 0; ks < 2; ++ks) {
      const int ko = ks * 32 + kg * 8;
      short8 af[4], b1f[4], b3f[4];
      #pragma unroll
      for (int mi = 0; mi < 4; ++mi)
        af[mi] = *(const short8*)(sA + (wm * 64 + mi * 16 + lr) * BK + ko);
      #pragma unroll
      for (int ni = 0; ni < 4; ++ni) {
        b1f[ni] = *(const short8*)(sB1 + (wn * 64 + ni * 16 + lr) * BK + ko);
        b3f[ni] = *(const short8*)(sB3 + (wn * 64 + ni * 16 + lr) * BK + ko);
      }
      #pragma unroll
      for (int mi = 0; mi < 4; ++mi)
        #pragma unroll
        for (int ni = 0; ni < 4; ++ni) {
          accg[mi][ni] = mfma_bf16(af[mi], b1f[ni], accg[mi][ni]);
          accu[mi][ni] = mfma_bf16(af[mi], b3f[ni], accu[mi][ni]);
        }
    }
    __syncthreads();
  }

  // --- epilogue: SwiGLU -> LDS h-tile -> coalesced 16B/lane row stores ---
  // C/D map col=lane&15, row=(lane>>4)*4+j  [m89-verified, R1/R2-passed]
  unsigned short* ht = smem;            // reuse staging LDS (loop is done)
  const int r0l = wm * 64 + kg * 4;
  const int c0l = wn * 64 + lr;
  #pragma unroll
  for (int mi = 0; mi < 4; ++mi)
    #pragma unroll
    for (int ni = 0; ni < 4; ++ni)
      #pragma unroll
      for (int j = 0; j < 4; ++j) {
        const float g  = accg[mi][ni][j];
        const float u  = accu[mi][ni][j];
        const float sg = g / (1.0f + __expf(-g));
        ht[(r0l + mi * 16 + j) * HLD + c0l + ni * 16] = f2bf(sg * u);
      }
  __syncthreads();

  const int orow = t >> 4;              // 0..15
  const int ocol = (t & 15) * 8;        // ushort col, 16 lanes x 16B = full row
  unsigned short* hg = h + (size_t)(bm * BM) * N + bn * BN;
  #pragma unroll
  for (int rr = 0; rr < 8; ++rr) {
    const int row = rr * 16 + orow;
    u16x8 v = *(const u16x8*)(ht + row * HLD + ocol);
    *(u16x8*)(hg + (size_t)row * N + ocol) = v;
  }
}

// ---------------------------------------------------------------------------
// Down GEMM: y = h @ w2b^T, fp32 out. Same ordering trick.
// ---------------------------------------------------------------------------
__global__ __launch_bounds__(256, 4)
void k_down2(const unsigned short* __restrict__ h,
             const unsigned short* __restrict__ w2b,
             float* __restrict__ y,
             int M, int N, int K) {
  __shared__ unsigned short smem2[2 * BM * BK];  // 32KB
  unsigned short* sA = smem2;
  unsigned short* sB = smem2 + BM * BK;

  const int t    = threadIdx.x;
  const int lane = t & 63;
  const int w    = t >> 6;
  const int wm   = w >> 1, wn = w & 1;
  const int lr   = lane & 15;
  const int kg   = lane >> 4;

  const int nwg = gridDim.x;
  const int per = nwg >> 3;
  const int wg  = (int)blockIdx.x;
  const int swz = (wg & 7) * per + (wg >> 3);
  const int bm  = swz & 15;        // M/BM = 16
  const int bn  = swz >> 4;

  const int srow  = lane >> 3;
  const int scolb = (lane & 7) * 16;

  f32x4 acc[4][4];
  #pragma unroll
  for (int i = 0; i < 4; ++i)
    #pragma unroll
    for (int j = 0; j < 4; ++j)
      #pragma unroll
      for (int e = 0; e < 4; ++e) acc[i][j][e] = 0.0f;

  const char* gA = (const char*)(h   + (size_t)bm * BM * K);
  const char* gB = (const char*)(w2b + (size_t)bn * BN * K);
  const size_t ldb = (size_t)K * 2;

  for (int kt = 0; kt < K; kt += BK) {
    #pragma unroll
    for (int i = 0; i < 4; ++i) {
      const int c = i * 4 + w;
      const size_t go = (size_t)(c * 8 + srow) * ldb + (size_t)kt * 2 + scolb;
      gl_lds16(gA + go, sA + c * 512);
      gl_lds16(gB + go, sB + c * 512);
    }
    __syncthreads();

    #pragma unroll
    for (int ks = 0; ks < 2; ++ks) {
      const int ko = ks * 32 + kg * 8;
      short8 af[4], bf[4];
      #pragma unroll
      for (int mi = 0; mi < 4; ++mi)
        af[mi] = *(const short8*)(sA + (wm * 64 + mi * 16 + lr) * BK + ko);
      #pragma unroll
      for (int ni = 0; ni < 4; ++ni)
        bf[ni] = *(const short8*)(sB + (wn * 64 + ni * 16 + lr) * BK + ko);
      #pragma unroll
      for (int mi = 0; mi < 4; ++mi)
        #pragma unroll
        for (int ni = 0; ni < 4; ++ni)
          acc[mi][ni] = mfma_bf16(af[mi], bf[ni], acc[mi][ni]);
    }
    __syncthreads();
  }

  // direct fp32 scatter stores (proven clean: R1 k_down WRITE_SIZE = 32.9MB)
  const int r0 = bm * BM + wm * 64 + kg * 4;
  const int c0 = bn * BN + wn * 64 + lr;
  #pragma unroll
  for (int mi = 0; mi < 4; ++mi)
    #pragma unroll
    for (int ni = 0; ni < 4; ++ni)
      #pragma unroll
      for (int j = 0; j < 4; ++j)
        y[(size_t)(r0 + mi * 16 + j) * N + (c0 + ni * 16)] = acc[mi][ni][j];
}

// ===========================================================================
// Fallback path (R1 kernels) if ws_size can't hold bf16 weight copies.
// ===========================================================================
#define LDK 72
__global__ __launch_bounds__(256, 2)
void k_gateup_fb(const float* __restrict__ x,
                 const float* __restrict__ w1, const float* __restrict__ w1s,
                 const float* __restrict__ w3, const float* __restrict__ w3s,
                 unsigned short* __restrict__ h,
                 int M, int N, int K) {
  __shared__ unsigned short sA[BM][LDK];
  __shared__ unsigned short sB1[BM][LDK];
  __shared__ unsigned short sB3[BM][LDK];
  const int t = threadIdx.x, bn = blockIdx.x, bm = blockIdx.y;
  const int lane = t & 63, wm = (t >> 6) >> 1, wn = (t >> 6) & 1;
  const int lr = lane & 15, kg = lane >> 4;
  f32x4 accg[4][4], accu[4][4];
  #pragma unroll
  for (int i = 0; i < 4; ++i)
    #pragma unroll
    for (int j = 0; j < 4; ++j)
      #pragma unroll
      for (int e = 0; e < 4; ++e) { accg[i][j][e] = 0.0f; accu[i][j][e] = 0.0f; }
  const int sc = (t & 15) << 2, sr0 = t >> 4, KB = K >> 7;
  const float* pA = x  + (size_t)(bm * BM + sr0) * K + sc;
  const float* p1 = w1 + (size_t)(bn * BN + sr0) * K + sc;
  const float* p3 = w3 + (size_t)(bn * BN + sr0) * K + sc;
  for (int kt = 0; kt < K; kt += BK) {
    const float s1 = w1s[bn * KB + (kt >> 7)];
    const float s3 = w3s[bn * KB + (kt >> 7)];
    #pragma unroll
    for (int i = 0; i < 8; ++i) {
      const int r = sr0 + i * 16;
      const size_t go = (size_t)i * 16 * K + kt;
      f32x4 va = *(const f32x4*)(pA + go);
      f32x4 v1 = *(const f32x4*)(p1 + go);
      f32x4 v3 = *(const f32x4*)(p3 + go);
      u16x4 qa, q1, q3;
      #pragma unroll
      for (int e = 0; e < 4; ++e) { qa[e] = f2bf(va[e]); q1[e] = f2bf(v1[e] * s1); q3[e] = f2bf(v3[e] * s3); }
      *(u16x4*)(&sA[r][sc]) = qa; *(u16x4*)(&sB1[r][sc]) = q1; *(u16x4*)(&sB3[r][sc]) = q3;
    }
    __syncthreads();
    #pragma unroll
    for (int ks = 0; ks < 2; ++ks) {
      const int ko = ks * 32 + kg * 8;
      short8 af[4], b1f[4], b3f[4];
      #pragma unroll
      for (int mi = 0; mi < 4; ++mi) af[mi] = *(const short8*)(&sA[wm * 64 + mi * 16 + lr][ko]);
      #pragma unroll
      for (int ni = 0; ni < 4; ++ni) { b1f[ni] = *(const short8*)(&sB1[wn * 64 + ni * 16 + lr][ko]); b3f[ni] = *(const short8*)(&sB3[wn * 64 + ni * 16 + lr][ko]); }
      #pragma unroll
      for (int mi = 0; mi < 4; ++mi)
        #pragma unroll
        for (int ni = 0; ni < 4; ++ni) { accg[mi][ni] = mfma_bf16(af[mi], b1f[ni], accg[mi][ni]); accu[mi][ni] = mfma_bf16(af[mi], b3f[ni], accu[mi][ni]); }
    }
    __syncthreads();
  }
  const int r0 = bm * BM + wm * 64 + kg * 4;
  const int c0 = bn * BN + wn * 64 + lr;
  #pragma unroll
  for (int mi = 0; mi < 4; ++mi)
    #pragma unroll
    for (int ni = 0; ni < 4; ++ni)
      #pragma unroll
      for (int j = 0; j < 4; ++j) {
        const float g = accg[mi][ni][j], u = accu[mi][ni][j];
        h[(size_t)(r0 + mi * 16 + j) * N + (c0 + ni * 16)] = f2bf((g / (1.0f + __expf(-g))) * u);
      }
}

__global__ __launch_bounds__(256, 2)
void k_down_fb(const unsigned short* __restrict__ h,
               const float* __restrict__ w2, const float* __restrict__ w2s,
               float* __restrict__ y, int M, int N, int K) {
  __shared__ unsigned short sA[BM][LDK];
  __shared__ unsigned short sB[BM][LDK];
  const int t = threadIdx.x, bn = blockIdx.x, bm = blockIdx.y;
  const int lane = t & 63, wm = (t >> 6) >> 1, wn = (t >> 6) & 1;
  const int lr = lane & 15, kg = lane >> 4;
  f32x4 acc[4][4];
  #pragma unroll
  for (int i = 0; i < 4; ++i)
    #pragma unroll
    for (int j = 0; j < 4; ++j)
      #pragma unroll
      for (int e = 0; e < 4; ++e) acc[i][j][e] = 0.0f;
  const int ac = (t & 7) << 3, ar0 = t >> 3;
  const int sc = (t & 15) << 2, sr0 = t >> 4, KB = K >> 7;
  const unsigned short* pA = h + (size_t)(bm * BM + ar0) * K + ac;
  const float* pB = w2 + (size_t)(bn * BN + sr0) * K + sc;
  for (int kt = 0; kt < K; kt += BK) {
    const float s2 = w2s[bn * KB + (kt >> 7)];
    #pragma unroll
    for (int i = 0; i < 4; ++i) { u16x8 v = *(const u16x8*)(pA + (size_t)i * 32 * K + kt); *(u16x8*)(&sA[ar0 + i * 32][ac]) = v; }
    #pragma unroll
    for (int i = 0; i < 8; ++i) {
      f32x4 v = *(const f32x4*)(pB + (size_t)i * 16 * K + kt);
      u16x4 q;
      #pragma unroll
      for (int e = 0; e < 4; ++e) q[e] = f2bf(v[e] * s2);
      *(u16x4*)(&sB[sr0 + i * 16][sc]) = q;
    }
    __syncthreads();
    #pragma unroll
    for (int ks = 0; ks < 2; ++ks) {
      const int ko = ks * 32 + kg * 8;
      short8 af[4], bf[4];
      #pragma unroll
      for (int mi = 0; mi < 4; ++mi) af[mi] = *(const short8*)(&sA[wm * 64 + mi * 16 + lr][ko]);
      #pragma unroll
      for (int ni = 0; ni < 4; ++ni) bf[ni] = *(const short8*)(&sB[wn * 64 + ni * 16 + lr][ko]);
      #pragma unroll
      for (int mi = 0; mi < 4; ++mi)
        #pragma unroll
        for (int ni = 0; ni < 4; ++ni) acc[mi][ni] = mfma_bf16(af[mi], bf[ni], acc[mi][ni]);
    }
    __syncthreads();
  }
  const int r0 = bm * BM + wm * 64 + kg * 4;
  const int c0 = bn * BN + wn * 64 + lr;
  #pragma unroll
  for (int mi = 0; mi < 4; ++mi)
    #pragma unroll
    for (int ni = 0; ni < 4; ++ni)
      #pragma unroll
      for (int j = 0; j < 4; ++j)
        y[(size_t)(r0 + mi * 16 + j) * N + (c0 + ni * 16)] = acc[mi][ni][j];
}

extern "C" void kernel_launch(void* const* d_in, const int* in_sizes, int n_in,
                              void* d_out, int out_size, void* d_ws, size_t ws_size,
                              hipStream_t stream) {
  const float* x   = (const float*)d_in[0];
  const float* w1  = (const float*)d_in[1];
  const float* w1s = (const float*)d_in[2];
  const float* w3  = (const float*)d_in[3];
  const float* w3s = (const float*)d_in[4];
  const float* w2  = (const float*)d_in[5];
  const float* w2s = (const float*)d_in[6];
  float* y = (float*)d_out;

  const int D = 4096, I = 14336;
  const int T = in_sizes[0] / D;          // 2048

  const size_t xbB  = (size_t)T * D * 2;
  const size_t wB   = (size_t)I * D * 2;
  const size_t hB   = (size_t)T * I * 2;
  const size_t need = xbB + 3 * wB + hB;  // ~408 MB

  if (ws_size >= need) {
    char* ws = (char*)d_ws;
    unsigned short* xb  = (unsigned short*)(ws);
    unsigned short* w1b = (unsigned short*)(ws + xbB);
    unsigned short* w3b = (unsigned short*)(ws + xbB + wB);
    unsigned short* w2b = (unsigned short*)(ws + xbB + 2 * wB);
    unsigned short* h   = (unsigned short*)(ws + xbB + 3 * wB);

    k_cvt_x<<<2048, 256, 0, stream>>>(x, xb, ((size_t)T * D) >> 3);
    k_cvt_w<<<2048, 256, 0, stream>>>(w1, w1s, w1b, I, D);
    k_cvt_w<<<2048, 256, 0, stream>>>(w3, w3s, w3b, I, D);
    k_cvt_w<<<2048, 256, 0, stream>>>(w2, w2s, w2b, D, I);

    k_gateup2<<<dim3((T / BM) * (I / BN)), dim3(256), 0, stream>>>(xb, w1b, w3b, h, T, I, D);
    k_down2  <<<dim3((T / BM) * (D / BN)), dim3(256), 0, stream>>>(h, w2b, y, T, D, I);
  } else {
    unsigned short* h = (unsigned short*)d_ws;
    k_gateup_fb<<<dim3(I / BN, T / BM), dim3(256), 0, stream>>>(x, w1, w1s, w3, w3s, h, T, I, D);
    k_down_fb  <<<dim3(D / BN, T / BM), dim3(256), 0, stream>>>(h, w2, w2s, y, T, D, I);
  }
}

// Round 4
// 1169.474 us; speedup vs baseline: 2.2739x; 2.1198x over previous
//
#include <hip/hip_runtime.h>
#include <hip/hip_bf16.h>
#include <stdint.h>

typedef __attribute__((ext_vector_type(8))) short short8;       // 8 bf16 (MFMA frag)
typedef __attribute__((ext_vector_type(4))) float f32x4;
typedef __attribute__((ext_vector_type(4))) unsigned short u16x4;
typedef __attribute__((ext_vector_type(8))) unsigned short u16x8;

#define BM 128
#define BN 128
#define BK 64
#define HLD 136   // h-tile epilogue LDS stride (128 + 8 pad)

static __device__ __forceinline__ unsigned short f2bf(float f) {
  union { float f; unsigned int u; } c; c.f = f;
  unsigned int u = c.u;
  u += 0x7FFFu + ((u >> 16) & 1u);
  return (unsigned short)(u >> 16);
}

static __device__ __forceinline__ f32x4 mfma_bf16(short8 a, short8 b, f32x4 c) {
  return __builtin_amdgcn_mfma_f32_16x16x32_bf16(a, b, c, 0, 0, 0);
}

// async global->LDS, 16B per lane. LDS dest = wave-uniform base + lane*16.
static __device__ __forceinline__ void gl_lds16(const void* g, void* lds) {
  __builtin_amdgcn_global_load_lds(
      (const __attribute__((address_space(1))) void*)(unsigned long long)(uintptr_t)g,
      (__attribute__((address_space(3))) void*)(unsigned int)(uintptr_t)lds,
      16, 0, 0);
}

// ---------------------------------------------------------------------------
// fp32 quantized weight [N][K] + block scale [N/128][K/128] -> dequant bf16
// ---------------------------------------------------------------------------
__global__ void k_cvt_w(const float* __restrict__ w, const float* __restrict__ s,
                        unsigned short* __restrict__ o, int N, int K) {
  const int KB = K >> 7;
  const size_t total = ((size_t)N * K) >> 3;
  for (size_t i = (size_t)blockIdx.x * blockDim.x + threadIdx.x; i < total;
       i += (size_t)gridDim.x * blockDim.x) {
    const size_t e = i << 3;
    const int n = (int)(e / K);
    const int k = (int)(e % K);
    const float sc = s[(n >> 7) * KB + (k >> 7)];
    f32x4 a = *(const f32x4*)(w + e);
    f32x4 b = *(const f32x4*)(w + e + 4);
    u16x8 q;
    #pragma unroll
    for (int j = 0; j < 4; ++j) { q[j] = f2bf(a[j] * sc); q[4 + j] = f2bf(b[j] * sc); }
    *(u16x8*)(o + e) = q;
  }
}

__global__ void k_cvt_x(const float* __restrict__ x, unsigned short* __restrict__ o,
                        size_t total8) {
  for (size_t i = (size_t)blockIdx.x * blockDim.x + threadIdx.x; i < total8;
       i += (size_t)gridDim.x * blockDim.x) {
    const size_t e = i << 3;
    f32x4 a = *(const f32x4*)(x + e);
    f32x4 b = *(const f32x4*)(x + e + 4);
    u16x8 q;
    #pragma unroll
    for (int j = 0; j < 4; ++j) { q[j] = f2bf(a[j]); q[4 + j] = f2bf(b[j]); }
    *(u16x8*)(o + e) = q;
  }
}

// ---------------------------------------------------------------------------
// Fused gate+up GEMM + SwiGLU, m97 structure, bf16 operands.
//   h = silu(xb @ w1b^T) * (xb @ w3b^T)   -> bf16 [M][N]
// NOTE register budget: accg+accu = 128 AGPR + ~84 VGPR ~= 212 regs/thread.
// __launch_bounds__(256,2) -> unified budget 256, NO SPILL. (256,3) spilled
// the accumulators to scratch: 5 GB/dispatch scratch traffic (R2/R3 bug).
// ---------------------------------------------------------------------------
__global__ __launch_bounds__(256, 2)
void k_gateup2(const unsigned short* __restrict__ xb,
               const unsigned short* __restrict__ w1b,
               const unsigned short* __restrict__ w3b,
               unsigned short* __restrict__ h,
               int M, int N, int K) {
  __shared__ unsigned short smem[3 * BM * BK];   // 48KB
  unsigned short* sA  = smem;
  unsigned short* sB1 = smem + BM * BK;
  unsigned short* sB3 = smem + 2 * BM * BK;

  const int t    = threadIdx.x;
  const int lane = t & 63;
  const int w    = t >> 6;
  const int wm   = w >> 1, wn = w & 1;
  const int lr   = lane & 15;
  const int kg   = lane >> 4;

  // XCD-chunked bijective swizzle (nwg % 8 == 0), bm fastest within chunk
  const int nwg = gridDim.x;
  const int per = nwg >> 3;
  const int wg  = (int)blockIdx.x;
  const int swz = (wg & 7) * per + (wg >> 3);
  const int bm  = swz & 15;        // M/BM = 16
  const int bn  = swz >> 4;

  const int srow  = lane >> 3;          // row within 8-row chunk
  const int scolb = (lane & 7) * 16;    // byte col within 128B row

  f32x4 accg[4][4], accu[4][4];
  #pragma unroll
  for (int i = 0; i < 4; ++i)
    #pragma unroll
    for (int j = 0; j < 4; ++j)
      #pragma unroll
      for (int e = 0; e < 4; ++e) { accg[i][j][e] = 0.0f; accu[i][j][e] = 0.0f; }

  const char* gA = (const char*)(xb  + (size_t)bm * BM * K);
  const char* g1 = (const char*)(w1b + (size_t)bn * BN * K);
  const char* g3 = (const char*)(w3b + (size_t)bn * BN * K);
  const size_t ldb = (size_t)K * 2;

  for (int kt = 0; kt < K; kt += BK) {
    #pragma unroll
    for (int i = 0; i < 4; ++i) {
      const int c = i * 4 + w;
      const size_t go = (size_t)(c * 8 + srow) * ldb + (size_t)kt * 2 + scolb;
      gl_lds16(gA + go, sA  + c * 512);
      gl_lds16(g1 + go, sB1 + c * 512);
      gl_lds16(g3 + go, sB3 + c * 512);
    }
    __syncthreads();

    #pragma unroll
    for (int ks = 0; ks < 2; ++ks) {
      const int ko = ks * 32 + kg * 8;
      short8 af[4], b1f[4], b3f[4];
      #pragma unroll
      for (int mi = 0; mi < 4; ++mi)
        af[mi] = *(const short8*)(sA + (wm * 64 + mi * 16 + lr) * BK + ko);
      #pragma unroll
      for (int ni = 0; ni < 4; ++ni) {
        b1f[ni] = *(const short8*)(sB1 + (wn * 64 + ni * 16 + lr) * BK + ko);
        b3f[ni] = *(const short8*)(sB3 + (wn * 64 + ni * 16 + lr) * BK + ko);
      }
      #pragma unroll
      for (int mi = 0; mi < 4; ++mi)
        #pragma unroll
        for (int ni = 0; ni < 4; ++ni) {
          accg[mi][ni] = mfma_bf16(af[mi], b1f[ni], accg[mi][ni]);
          accu[mi][ni] = mfma_bf16(af[mi], b3f[ni], accu[mi][ni]);
        }
    }
    __syncthreads();
  }

  // epilogue: SwiGLU -> LDS h-tile -> coalesced 16B/lane row stores
  // C/D map col=lane&15, row=(lane>>4)*4+j  [m89-verified, R1/R2-passed]
  unsigned short* ht = smem;            // reuse staging LDS
  const int r0l = wm * 64 + kg * 4;
  const int c0l = wn * 64 + lr;
  #pragma unroll
  for (int mi = 0; mi < 4; ++mi)
    #pragma unroll
    for (int ni = 0; ni < 4; ++ni)
      #pragma unroll
      for (int j = 0; j < 4; ++j) {
        const float g  = accg[mi][ni][j];
        const float u  = accu[mi][ni][j];
        const float sg = g / (1.0f + __expf(-g));
        ht[(r0l + mi * 16 + j) * HLD + c0l + ni * 16] = f2bf(sg * u);
      }
  __syncthreads();

  const int orow = t >> 4;              // 0..15
  const int ocol = (t & 15) * 8;        // 16 lanes x 16B = full 256B row
  unsigned short* hg = h + (size_t)(bm * BM) * N + bn * BN;
  #pragma unroll
  for (int rr = 0; rr < 8; ++rr) {
    const int row = rr * 16 + orow;
    u16x8 v = *(const u16x8*)(ht + row * HLD + ocol);
    *(u16x8*)(hg + (size_t)row * N + ocol) = v;
  }
}

// ---------------------------------------------------------------------------
// Down GEMM: y = h @ w2b^T, fp32 out.
// Budget: 64 AGPR acc + ~84 VGPR ~= 150 -> (256,3) budget ~170, no spill.
// ---------------------------------------------------------------------------
__global__ __launch_bounds__(256, 3)
void k_down2(const unsigned short* __restrict__ h,
             const unsigned short* __restrict__ w2b,
             float* __restrict__ y,
             int M, int N, int K) {
  __shared__ unsigned short smem2[2 * BM * BK];  // 32KB
  unsigned short* sA = smem2;
  unsigned short* sB = smem2 + BM * BK;

  const int t    = threadIdx.x;
  const int lane = t & 63;
  const int w    = t >> 6;
  const int wm   = w >> 1, wn = w & 1;
  const int lr   = lane & 15;
  const int kg   = lane >> 4;

  const int nwg = gridDim.x;
  const int per = nwg >> 3;
  const int wg  = (int)blockIdx.x;
  const int swz = (wg & 7) * per + (wg >> 3);
  const int bm  = swz & 15;        // M/BM = 16
  const int bn  = swz >> 4;

  const int srow  = lane >> 3;
  const int scolb = (lane & 7) * 16;

  f32x4 acc[4][4];
  #pragma unroll
  for (int i = 0; i < 4; ++i)
    #pragma unroll
    for (int j = 0; j < 4; ++j)
      #pragma unroll
      for (int e = 0; e < 4; ++e) acc[i][j][e] = 0.0f;

  const char* gA = (const char*)(h   + (size_t)bm * BM * K);
  const char* gB = (const char*)(w2b + (size_t)bn * BN * K);
  const size_t ldb = (size_t)K * 2;

  for (int kt = 0; kt < K; kt += BK) {
    #pragma unroll
    for (int i = 0; i < 4; ++i) {
      const int c = i * 4 + w;
      const size_t go = (size_t)(c * 8 + srow) * ldb + (size_t)kt * 2 + scolb;
      gl_lds16(gA + go, sA + c * 512);
      gl_lds16(gB + go, sB + c * 512);
    }
    __syncthreads();

    #pragma unroll
    for (int ks = 0; ks < 2; ++ks) {
      const int ko = ks * 32 + kg * 8;
      short8 af[4], bf[4];
      #pragma unroll
      for (int mi = 0; mi < 4; ++mi)
        af[mi] = *(const short8*)(sA + (wm * 64 + mi * 16 + lr) * BK + ko);
      #pragma unroll
      for (int ni = 0; ni < 4; ++ni)
        bf[ni] = *(const short8*)(sB + (wn * 64 + ni * 16 + lr) * BK + ko);
      #pragma unroll
      for (int mi = 0; mi < 4; ++mi)
        #pragma unroll
        for (int ni = 0; ni < 4; ++ni)
          acc[mi][ni] = mfma_bf16(af[mi], bf[ni], acc[mi][ni]);
    }
    __syncthreads();
  }

  const int r0 = bm * BM + wm * 64 + kg * 4;
  const int c0 = bn * BN + wn * 64 + lr;
  #pragma unroll
  for (int mi = 0; mi < 4; ++mi)
    #pragma unroll
    for (int ni = 0; ni < 4; ++ni)
      #pragma unroll
      for (int j = 0; j < 4; ++j)
        y[(size_t)(r0 + mi * 16 + j) * N + (c0 + ni * 16)] = acc[mi][ni][j];
}

// ===========================================================================
// Fallback path (R1 kernels) if ws_size can't hold bf16 weight copies.
// ===========================================================================
#define LDK 72
__global__ __launch_bounds__(256, 2)
void k_gateup_fb(const float* __restrict__ x,
                 const float* __restrict__ w1, const float* __restrict__ w1s,
                 const float* __restrict__ w3, const float* __restrict__ w3s,
                 unsigned short* __restrict__ h,
                 int M, int N, int K) {
  __shared__ unsigned short sA[BM][LDK];
  __shared__ unsigned short sB1[BM][LDK];
  __shared__ unsigned short sB3[BM][LDK];
  const int t = threadIdx.x, bn = blockIdx.x, bm = blockIdx.y;
  const int lane = t & 63, wm = (t >> 6) >> 1, wn = (t >> 6) & 1;
  const int lr = lane & 15, kg = lane >> 4;
  f32x4 accg[4][4], accu[4][4];
  #pragma unroll
  for (int i = 0; i < 4; ++i)
    #pragma unroll
    for (int j = 0; j < 4; ++j)
      #pragma unroll
      for (int e = 0; e < 4; ++e) { accg[i][j][e] = 0.0f; accu[i][j][e] = 0.0f; }
  const int sc = (t & 15) << 2, sr0 = t >> 4, KB = K >> 7;
  const float* pA = x  + (size_t)(bm * BM + sr0) * K + sc;
  const float* p1 = w1 + (size_t)(bn * BN + sr0) * K + sc;
  const float* p3 = w3 + (size_t)(bn * BN + sr0) * K + sc;
  for (int kt = 0; kt < K; kt += BK) {
    const float s1 = w1s[bn * KB + (kt >> 7)];
    const float s3 = w3s[bn * KB + (kt >> 7)];
    #pragma unroll
    for (int i = 0; i < 8; ++i) {
      const int r = sr0 + i * 16;
      const size_t go = (size_t)i * 16 * K + kt;
      f32x4 va = *(const f32x4*)(pA + go);
      f32x4 v1 = *(const f32x4*)(p1 + go);
      f32x4 v3 = *(const f32x4*)(p3 + go);
      u16x4 qa, q1, q3;
      #pragma unroll
      for (int e = 0; e < 4; ++e) { qa[e] = f2bf(va[e]); q1[e] = f2bf(v1[e] * s1); q3[e] = f2bf(v3[e] * s3); }
      *(u16x4*)(&sA[r][sc]) = qa; *(u16x4*)(&sB1[r][sc]) = q1; *(u16x4*)(&sB3[r][sc]) = q3;
    }
    __syncthreads();
    #pragma unroll
    for (int ks = 0; ks < 2; ++ks) {
      const int ko = ks * 32 + kg * 8;
      short8 af[4], b1f[4], b3f[4];
      #pragma unroll
      for (int mi = 0; mi < 4; ++mi) af[mi] = *(const short8*)(&sA[wm * 64 + mi * 16 + lr][ko]);
      #pragma unroll
      for (int ni = 0; ni < 4; ++ni) { b1f[ni] = *(const short8*)(&sB1[wn * 64 + ni * 16 + lr][ko]); b3f[ni] = *(const short8*)(&sB3[wn * 64 + ni * 16 + lr][ko]); }
      #pragma unroll
      for (int mi = 0; mi < 4; ++mi)
        #pragma unroll
        for (int ni = 0; ni < 4; ++ni) { accg[mi][ni] = mfma_bf16(af[mi], b1f[ni], accg[mi][ni]); accu[mi][ni] = mfma_bf16(af[mi], b3f[ni], accu[mi][ni]); }
    }
    __syncthreads();
  }
  const int r0 = bm * BM + wm * 64 + kg * 4;
  const int c0 = bn * BN + wn * 64 + lr;
  #pragma unroll
  for (int mi = 0; mi < 4; ++mi)
    #pragma unroll
    for (int ni = 0; ni < 4; ++ni)
      #pragma unroll
      for (int j = 0; j < 4; ++j) {
        const float g = accg[mi][ni][j], u = accu[mi][ni][j];
        h[(size_t)(r0 + mi * 16 + j) * N + (c0 + ni * 16)] = f2bf((g / (1.0f + __expf(-g))) * u);
      }
}

__global__ __launch_bounds__(256, 2)
void k_down_fb(const unsigned short* __restrict__ h,
               const float* __restrict__ w2, const float* __restrict__ w2s,
               float* __restrict__ y, int M, int N, int K) {
  __shared__ unsigned short sA[BM][LDK];
  __shared__ unsigned short sB[BM][LDK];
  const int t = threadIdx.x, bn = blockIdx.x, bm = blockIdx.y;
  const int lane = t & 63, wm = (t >> 6) >> 1, wn = (t >> 6) & 1;
  const int lr = lane & 15, kg = lane >> 4;
  f32x4 acc[4][4];
  #pragma unroll
  for (int i = 0; i < 4; ++i)
    #pragma unroll
    for (int j = 0; j < 4; ++j)
      #pragma unroll
      for (int e = 0; e < 4; ++e) acc[i][j][e] = 0.0f;
  const int ac = (t & 7) << 3, ar0 = t >> 3;
  const int sc = (t & 15) << 2, sr0 = t >> 4, KB = K >> 7;
  const unsigned short* pA = h + (size_t)(bm * BM + ar0) * K + ac;
  const float* pB = w2 + (size_t)(bn * BN + sr0) * K + sc;
  for (int kt = 0; kt < K; kt += BK) {
    const float s2 = w2s[bn * KB + (kt >> 7)];
    #pragma unroll
    for (int i = 0; i < 4; ++i) { u16x8 v = *(const u16x8*)(pA + (size_t)i * 32 * K + kt); *(u16x8*)(&sA[ar0 + i * 32][ac]) = v; }
    #pragma unroll
    for (int i = 0; i < 8; ++i) {
      f32x4 v = *(const f32x4*)(pB + (size_t)i * 16 * K + sc * 0 + kt);
      u16x4 q;
      #pragma unroll
      for (int e = 0; e < 4; ++e) q[e] = f2bf(v[e] * s2);
      *(u16x4*)(&sB[sr0 + i * 16][sc]) = q;
    }
    __syncthreads();
    #pragma unroll
    for (int ks = 0; ks < 2; ++ks) {
      const int ko = ks * 32 + kg * 8;
      short8 af[4], bf[4];
      #pragma unroll
      for (int mi = 0; mi < 4; ++mi) af[mi] = *(const short8*)(&sA[wm * 64 + mi * 16 + lr][ko]);
      #pragma unroll
      for (int ni = 0; ni < 4; ++ni) bf[ni] = *(const short8*)(&sB[wn * 64 + ni * 16 + lr][ko]);
      #pragma unroll
      for (int mi = 0; mi < 4; ++mi)
        #pragma unroll
        for (int ni = 0; ni < 4; ++ni) acc[mi][ni] = mfma_bf16(af[mi], bf[ni], acc[mi][ni]);
    }
    __syncthreads();
  }
  const int r0 = bm * BM + wm * 64 + kg * 4;
  const int c0 = bn * BN + wn * 64 + lr;
  #pragma unroll
  for (int mi = 0; mi < 4; ++mi)
    #pragma unroll
    for (int ni = 0; ni < 4; ++ni)
      #pragma unroll
      for (int j = 0; j < 4; ++j)
        y[(size_t)(r0 + mi * 16 + j) * N + (c0 + ni * 16)] = acc[mi][ni][j];
}

extern "C" void kernel_launch(void* const* d_in, const int* in_sizes, int n_in,
                              void* d_out, int out_size, void* d_ws, size_t ws_size,
                              hipStream_t stream) {
  const float* x   = (const float*)d_in[0];
  const float* w1  = (const float*)d_in[1];
  const float* w1s = (const float*)d_in[2];
  const float* w3  = (const float*)d_in[3];
  const float* w3s = (const float*)d_in[4];
  const float* w2  = (const float*)d_in[5];
  const float* w2s = (const float*)d_in[6];
  float* y = (float*)d_out;

  const int D = 4096, I = 14336;
  const int T = in_sizes[0] / D;          // 2048

  const size_t xbB  = (size_t)T * D * 2;
  const size_t wB   = (size_t)I * D * 2;
  const size_t hB   = (size_t)T * I * 2;
  const size_t need = xbB + 3 * wB + hB;  // ~408 MB

  if (ws_size >= need) {
    char* ws = (char*)d_ws;
    unsigned short* xb  = (unsigned short*)(ws);
    unsigned short* w1b = (unsigned short*)(ws + xbB);
    unsigned short* w3b = (unsigned short*)(ws + xbB + wB);
    unsigned short* w2b = (unsigned short*)(ws + xbB + 2 * wB);
    unsigned short* h   = (unsigned short*)(ws + xbB + 3 * wB);

    k_cvt_x<<<2048, 256, 0, stream>>>(x, xb, ((size_t)T * D) >> 3);
    k_cvt_w<<<2048, 256, 0, stream>>>(w1, w1s, w1b, I, D);
    k_cvt_w<<<2048, 256, 0, stream>>>(w3, w3s, w3b, I, D);
    k_cvt_w<<<2048, 256, 0, stream>>>(w2, w2s, w2b, D, I);

    k_gateup2<<<dim3((T / BM) * (I / BN)), dim3(256), 0, stream>>>(xb, w1b, w3b, h, T, I, D);
    k_down2  <<<dim3((T / BM) * (D / BN)), dim3(256), 0, stream>>>(h, w2b, y, T, D, I);
  } else {
    unsigned short* h = (unsigned short*)d_ws;
    k_gateup_fb<<<dim3(I / BN, T / BM), dim3(256), 0, stream>>>(x, w1, w1s, w3, w3s, h, T, I, D);
    k_down_fb  <<<dim3(D / BN, T / BM), dim3(256), 0, stream>>>(h, w2, w2s, y, T, D, I);
  }
}

// Round 5
// 907.182 us; speedup vs baseline: 2.9314x; 1.2891x over previous
//
#include <hip/hip_runtime.h>
#include <hip/hip_bf16.h>
#include <stdint.h>

typedef __attribute__((ext_vector_type(8))) short short8;       // 8 bf16 (MFMA frag)
typedef __attribute__((ext_vector_type(4))) float f32x4;
typedef __attribute__((ext_vector_type(8))) unsigned short u16x8;

static __device__ __forceinline__ unsigned short f2bf(float f) {
  union { float f; unsigned int u; } c; c.f = f;
  unsigned int u = c.u;
  u += 0x7FFFu + ((u >> 16) & 1u);
  return (unsigned short)(u >> 16);
}
static __device__ __forceinline__ float bf2f(unsigned short h) {
  union { unsigned int u; float f; } c; c.u = ((unsigned int)h) << 16;
  return c.f;
}
static __device__ __forceinline__ f32x4 mfma_bf16(short8 a, short8 b, f32x4 c) {
  return __builtin_amdgcn_mfma_f32_16x16x32_bf16(a, b, c, 0, 0, 0);
}
// async global->LDS, 16B/lane; LDS dest = wave-uniform base + lane*16
static __device__ __forceinline__ void gl_lds16(const void* g, void* lds) {
  __builtin_amdgcn_global_load_lds(
      (const __attribute__((address_space(1))) void*)(unsigned long long)(uintptr_t)g,
      (__attribute__((address_space(3))) void*)(unsigned int)(uintptr_t)lds,
      16, 0, 0);
}

// ---------------------------------------------------------------------------
// convert kernels (dequant weights to bf16; x to bf16)
// ---------------------------------------------------------------------------
__global__ void k_cvt_w(const float* __restrict__ w, const float* __restrict__ s,
                        unsigned short* __restrict__ o, int N, int K) {
  const int KB = K >> 7;
  const size_t total = ((size_t)N * K) >> 3;
  for (size_t i = (size_t)blockIdx.x * blockDim.x + threadIdx.x; i < total;
       i += (size_t)gridDim.x * blockDim.x) {
    const size_t e = i << 3;
    const int n = (int)(e / K);
    const int k = (int)(e % K);
    const float sc = s[(n >> 7) * KB + (k >> 7)];
    f32x4 a = *(const f32x4*)(w + e);
    f32x4 b = *(const f32x4*)(w + e + 4);
    u16x8 q;
    #pragma unroll
    for (int j = 0; j < 4; ++j) { q[j] = f2bf(a[j] * sc); q[4 + j] = f2bf(b[j] * sc); }
    *(u16x8*)(o + e) = q;
  }
}

__global__ void k_cvt_x(const float* __restrict__ x, unsigned short* __restrict__ o,
                        size_t total8) {
  for (size_t i = (size_t)blockIdx.x * blockDim.x + threadIdx.x; i < total8;
       i += (size_t)gridDim.x * blockDim.x) {
    const size_t e = i << 3;
    f32x4 a = *(const f32x4*)(x + e);
    f32x4 b = *(const f32x4*)(x + e + 4);
    u16x8 q;
    #pragma unroll
    for (int j = 0; j < 4; ++j) { q[j] = f2bf(a[j]); q[4 + j] = f2bf(b[j]); }
    *(u16x8*)(o + e) = q;
  }
}

// ---------------------------------------------------------------------------
// 256-row deep-pipelined GEMM:  C[M][N] (+epilogue) = A[M][K] @ B[N][K]^T
// bf16 operands. 512 threads = 8 waves (2x4). BM=256, BN=128*NB, BK=64.
// LDS: ring-4 of 16KB half-tiles per operand (128KB). Counted vmcnt
// (never 0 in steady state); raw s_barrier; reads->regs before DMA
// overwrite (race-free by construction).
// Swizzle: byte ^= (row&7)<<4, write side via pre-swizzled global source,
// read side on ds_read address (involution, both sides).
// EPI: 0 = store bf16; 1 = h = silu(Gin)*acc -> bf16 (in-place over Gin ok);
//      2 = store f32.
// ---------------------------------------------------------------------------
template<int NB, int EPI>
__global__ __launch_bounds__(512, 2)
void k_gemm256(const unsigned short* __restrict__ A,
               const unsigned short* __restrict__ B,
               const unsigned short* Gin,
               void* Out,
               int M, int N, int K) {
  constexpr int BN   = NB * 128;
  constexpr int NREP = NB * 2;           // 16-col frags per wave
  __shared__ unsigned short lds[65536];  // A: 4 x 8192, B: 4 x 8192 (ushorts)

  const int tid  = threadIdx.x;
  const int lane = tid & 63;
  const int wid  = tid >> 6;
  const int wm   = wid >> 2;             // 0..1
  const int wn   = wid & 3;              // 0..3
  const int lr   = lane & 15;
  const int kg   = lane >> 4;
  const int xr   = (lr & 7) << 4;        // read-side XOR (row&7)<<4

  // XCD-chunked bijective swizzle, bm fastest (M/256 == 8)
  const int nwg = gridDim.x;
  const int per = nwg >> 3;
  const int wg  = (int)blockIdx.x;
  const int swz = (wg & 7) * per + (wg >> 3);
  const int bm  = swz & 7;
  const int bn  = swz >> 3;

  // staging geometry (per thread, fixed): linear L = tid*16 + j*8192 within a
  // 128x64 half; logical U = L ^ ((row&7)<<4); row unchanged, col pre-swizzled
  const int r0   = tid >> 3;                                   // 0..63
  const int colb = ((tid & 7) ^ ((tid >> 3) & 7)) << 4;        // byte col
  const size_t ldb = (size_t)K * 2;

  const char* gA = (const char*)A + (size_t)bm * 256 * ldb;
  const char* gB = (const char*)B + (size_t)bn * BN * ldb;

  const int NT = K >> 6;

  auto stage = [&](int t) {
    const size_t kb = (size_t)t * 128;   // K-tile byte offset in a row
    #pragma unroll
    for (int h = 0; h < 2; ++h) {        // A halves
      unsigned short* d = lds + (((2 * t + h) & 3) * 8192) + wid * 512;
      const char* s = gA + (size_t)(h * 128 + r0) * ldb + kb + colb;
      gl_lds16(s,            d);
      gl_lds16(s + 64 * ldb, d + 4096);
    }
    #pragma unroll
    for (int h = 0; h < NB; ++h) {       // B halves
      unsigned short* d = lds + 32768 + (((NB * t + h) & 3) * 8192) + wid * 512;
      const char* s = gB + (size_t)(h * 128 + r0) * ldb + kb + colb;
      gl_lds16(s,            d);
      gl_lds16(s + 64 * ldb, d + 4096);
    }
  };

  f32x4 acc[8][NREP];
  #pragma unroll
  for (int m = 0; m < 8; ++m)
    #pragma unroll
    for (int n = 0; n < NREP; ++n)
      #pragma unroll
      for (int e = 0; e < 4; ++e) acc[m][n][e] = 0.0f;

  const int wrow0 = (NB == 2) ? (wn & 1) * 64 : wn * 32;  // row base in B-half
  const int bhalf = (NB == 2) ? (wn >> 1) : 0;

  stage(0);
  stage(1);

  for (int t = 0; t < NT; ++t) {
    // tile t ready; tile t+1 stays in flight (counted vmcnt, never 0 mid-loop)
    if (t == NT - 1) {
      asm volatile("s_waitcnt vmcnt(0)" ::: "memory");
    } else if constexpr (NB == 2) {
      asm volatile("s_waitcnt vmcnt(8)" ::: "memory");
    } else {
      asm volatile("s_waitcnt vmcnt(6)" ::: "memory");
    }
    __builtin_amdgcn_s_barrier();
    __builtin_amdgcn_sched_barrier(0);

    const char* ab = (const char*)lds + (((2 * t + wm) & 3) * 16384);
    const char* bb = (const char*)lds + 65536 + (((NB * t + bhalf) & 3) * 16384);

    short8 a0[8], b0[NREP], a1[8], b1[NREP];
    #pragma unroll
    for (int m = 0; m < 8; ++m)
      a0[m] = *(const short8*)(ab + ((((m * 16 + lr) * 128) + kg * 16) ^ xr));
    #pragma unroll
    for (int n = 0; n < NREP; ++n)
      b0[n] = *(const short8*)(bb + ((((wrow0 + n * 16 + lr) * 128) + kg * 16) ^ xr));
    #pragma unroll
    for (int m = 0; m < 8; ++m)
      #pragma unroll
      for (int n = 0; n < NREP; ++n)
        acc[m][n] = mfma_bf16(a0[m], b0[n], acc[m][n]);

    #pragma unroll
    for (int m = 0; m < 8; ++m)
      a1[m] = *(const short8*)(ab + ((((m * 16 + lr) * 128) + 64 + kg * 16) ^ xr));
    #pragma unroll
    for (int n = 0; n < NREP; ++n)
      b1[n] = *(const short8*)(bb + ((((wrow0 + n * 16 + lr) * 128) + 64 + kg * 16) ^ xr));

    // all LDS reads retired -> safe for other waves' DMA to overwrite
    asm volatile("s_waitcnt lgkmcnt(0)" ::: "memory");
    __builtin_amdgcn_s_barrier();
    __builtin_amdgcn_sched_barrier(0);
    if (t + 2 < NT) stage(t + 2);
    __builtin_amdgcn_sched_barrier(0);

    #pragma unroll
    for (int m = 0; m < 8; ++m)
      #pragma unroll
      for (int n = 0; n < NREP; ++n)
        acc[m][n] = mfma_bf16(a1[m], b1[n], acc[m][n]);
  }

  // epilogue: C/D map col=lane&15, row=(lane>>4)*4+j  [m89-verified, R1-R4]
  const int growb = bm * 256 + wm * 128 + kg * 4;
  const int gcolb = bn * BN + wn * (BN / 4) + lr;
  #pragma unroll
  for (int m = 0; m < 8; ++m)
    #pragma unroll
    for (int n = 0; n < NREP; ++n)
      #pragma unroll
      for (int j = 0; j < 4; ++j) {
        const size_t idx = (size_t)(growb + m * 16 + j) * N + (gcolb + n * 16);
        if constexpr (EPI == 0) {
          ((unsigned short*)Out)[idx] = f2bf(acc[m][n][j]);
        } else if constexpr (EPI == 1) {
          const float gv = bf2f(Gin[idx]);
          const float sg = gv / (1.0f + __expf(-gv));
          ((unsigned short*)Out)[idx] = f2bf(sg * acc[m][n][j]);
        } else {
          ((float*)Out)[idx] = acc[m][n][j];
        }
      }
}

extern "C" void kernel_launch(void* const* d_in, const int* in_sizes, int n_in,
                              void* d_out, int out_size, void* d_ws, size_t ws_size,
                              hipStream_t stream) {
  const float* x   = (const float*)d_in[0];
  const float* w1  = (const float*)d_in[1];
  const float* w1s = (const float*)d_in[2];
  const float* w3  = (const float*)d_in[3];
  const float* w3s = (const float*)d_in[4];
  const float* w2  = (const float*)d_in[5];
  const float* w2s = (const float*)d_in[6];
  float* y = (float*)d_out;

  const int D = 4096, I = 14336;
  const int T = in_sizes[0] / D;          // 2048

  const size_t xbB = (size_t)T * D * 2;   //  16.8 MB
  const size_t wB  = (size_t)I * D * 2;   // 117.4 MB each
  const size_t gB_ = (size_t)T * I * 2;   //  58.7 MB (g, then h in-place)

  char* ws = (char*)d_ws;
  unsigned short* xb  = (unsigned short*)(ws);
  unsigned short* w1b = (unsigned short*)(ws + xbB);
  unsigned short* w3b = (unsigned short*)(ws + xbB + wB);
  unsigned short* w2b = (unsigned short*)(ws + xbB + 2 * wB);
  unsigned short* g   = (unsigned short*)(ws + xbB + 3 * wB);   // g -> h in place

  k_cvt_x<<<2048, 256, 0, stream>>>(x, xb, ((size_t)T * D) >> 3);
  k_cvt_w<<<2048, 256, 0, stream>>>(w1, w1s, w1b, I, D);
  k_cvt_w<<<2048, 256, 0, stream>>>(w3, w3s, w3b, I, D);
  k_cvt_w<<<2048, 256, 0, stream>>>(w2, w2s, w2b, D, I);

  // gate: g = xb @ w1b^T            (bf16 out)      grid 8*56 = 448
  k_gemm256<2, 0><<<dim3((T / 256) * (I / 256)), dim3(512), 0, stream>>>(
      xb, w1b, nullptr, g, T, I, D);
  // up:   h = silu(g) * (xb @ w3b^T), in-place over g
  k_gemm256<2, 1><<<dim3((T / 256) * (I / 256)), dim3(512), 0, stream>>>(
      xb, w3b, g, g, T, I, D);
  // down: y = h @ w2b^T             (f32 out)       grid 8*32 = 256 (BN=128)
  k_gemm256<1, 2><<<dim3((T / 256) * (D / 128)), dim3(512), 0, stream>>>(
      g, w2b, nullptr, y, T, D, I);
}